// Round 6
// baseline (109.748 us; speedup 1.0000x reference)
//
#include <hip/hip_runtime.h>
#include <math.h>

#define N 8192
#define D 64
#define CHUNKS 512
#define CROWS 16
#define NSUP 32  // super-chunks of 16 chunks

typedef unsigned long long u64;

__device__ __forceinline__ unsigned ordered_bits(float v) {
  unsigned u = __float_as_uint(v);
  return u ^ (((int)u >> 31) | 0x80000000u);
}

// K1: h = x@Wt (Wt column in regs, x row via shfl broadcast); f1/f2; 64-bit
// strictly-distinct sort keys + per-row threshold keys. 16 rows/block.
// Block 0 additionally zeroes the super-chunk total region (4160 floats)
// that K3 accumulates into with atomics (workspace arrives poisoned).
__global__ __launch_bounds__(256) void k1_gemm(
    const float* __restrict__ x, const float* __restrict__ Wt,
    const float* __restrict__ a1, const float* __restrict__ b1,
    const float* __restrict__ a2, const float* __restrict__ b2,
    float* __restrict__ h, float* __restrict__ f1, float* __restrict__ f2,
    u64* __restrict__ key64, u64* __restrict__ thrkey,
    float* __restrict__ supz) {
  int t = threadIdx.x;
  int lane = t & 63, wv = t >> 6;
  if (blockIdx.x == 0) {
    for (int i = t; i < 2 * NSUP * D + 2 * NSUP; i += 256) supz[i] = 0.f;
  }
  float wcol[D];
#pragma unroll
  for (int k = 0; k < D; ++k) wcol[k] = Wt[k * D + lane];  // coalesced
  float a1d = a1[lane], a2d = a2[lane];
  float b1v = b1[0], b2v = b2[0];
  int rowBase = blockIdx.x * 16;
#pragma unroll
  for (int it = 0; it < 4; ++it) {
    int grow = rowBase + wv + it * 4;
    float xv = x[grow * D + lane];
    float acc = 0.f;
#pragma unroll
    for (int k = 0; k < D; ++k) acc += __shfl(xv, k) * wcol[k];
    h[grow * D + lane] = acc;
    float v1 = acc * a1d, v2 = acc * a2d;
#pragma unroll
    for (int off = 32; off > 0; off >>= 1) {
      v1 += __shfl_xor(v1, off);
      v2 += __shfl_xor(v2, off);
    }
    if (lane == 0) {
      float F1 = v1 + b1v, F2 = v2 + b2v;
      f1[grow] = F1;
      f2[grow] = F2;
      key64[grow] = ((u64)ordered_bits(F2) << 13) | (unsigned)grow;
      thrkey[grow] = ((u64)ordered_bits(-F1) << 13);
    }
  }
}

// K2: counting rank for the 8192 KEY queries only (half the old compares).
// 512 blocks x 256 thr; block owns 16 queries (4/wave, 4/thread). All 8192
// keys streamed via LDS in two 4096-key tiles; each lane scans its own
// 64-key slice (bank-staggered), full-wave shfl_xor reduce. Scatter writes
// perm/wsm/wbg AND skey[rank]=key (sorted keys for the bsearch in K3).
__global__ __launch_bounds__(256) void k2_rank(
    const u64* __restrict__ key64, const float* __restrict__ f2,
    int* __restrict__ perm, float* __restrict__ wsm, float* __restrict__ wbg,
    u64* __restrict__ skey) {
  __shared__ u64 ksl[4096];  // 32 KiB
  int t = threadIdx.x;
  int lane = t & 63, wv = t >> 6;
  int qbase = blockIdx.x * 16 + wv * 4;
  u64 qv[4];
#pragma unroll
  for (int qi = 0; qi < 4; ++qi) qv[qi] = key64[qbase + qi];
  int cnt[4] = {0, 0, 0, 0};
#pragma unroll
  for (int p = 0; p < 2; ++p) {
    const u64* kp = key64 + p * 4096;
#pragma unroll
    for (int i = 0; i < 16; ++i) ksl[t + i * 256] = kp[t + i * 256];
    __syncthreads();
    const u64* kb = ksl + lane * 64;
#pragma unroll 8
    for (int j = 0; j < 64; ++j) {
      int jj = (j + lane) & 63;  // bank stagger across lanes
      u64 k = kb[jj];
      cnt[0] += (k < qv[0]) ? 1 : 0;
      cnt[1] += (k < qv[1]) ? 1 : 0;
      cnt[2] += (k < qv[2]) ? 1 : 0;
      cnt[3] += (k < qv[3]) ? 1 : 0;
    }
    __syncthreads();  // all reads done before next tile overwrites ksl
  }
#pragma unroll
  for (int off = 1; off < 64; off <<= 1) {
#pragma unroll
    for (int qi = 0; qi < 4; ++qi) cnt[qi] += __shfl_xor(cnt[qi], off);
  }
  if (lane == 0) {
#pragma unroll
    for (int qi = 0; qi < 4; ++qi) {
      int q = qbase + qi;
      int rank = cnt[qi];
      float v = f2[q];
      perm[rank] = q;
      wsm[rank] = expf(0.2f * v);
      wbg[rank] = expf(v);
      skey[rank] = qv[qi];
    }
  }
}

// K3: blocks 0..127: per-chunk LOCAL scans (1 chunk/wave, registers only) +
// chunk totals + atomic super-chunk totals. Blocks 128..159: ksplit via
// binary search of thrkey in sorted skey (staged in 64KB LDS), 256/block.
__global__ __launch_bounds__(256) void k3_scan(
    const float* __restrict__ h, const int* __restrict__ perm,
    const float* __restrict__ wsm, const float* __restrict__ wbg,
    const u64* __restrict__ skey, const u64* __restrict__ thrkey,
    float* __restrict__ Pl, float* __restrict__ Sl,
    float* __restrict__ pl, float* __restrict__ sl,
    float* __restrict__ tot_s, float* __restrict__ tot_b,
    float* __restrict__ tots_sc, float* __restrict__ totb_sc,
    float* __restrict__ sup_s, float* __restrict__ sup_b,
    float* __restrict__ sups_c, float* __restrict__ supb_c,
    int* __restrict__ ksplit) {
  __shared__ u64 sk[N];  // 64 KiB, used only by search blocks
  int t = threadIdx.x, lane = t & 63, wv = t >> 6;
  int bid = blockIdx.x;
  if (bid < 128) {
    int c = bid * 4 + wv;
    int base = c * CROWS;
    int dd = lane;
    int pj = (dd < CROWS) ? perm[base + dd] : 0;
    float wS = (dd < CROWS) ? wsm[base + dd] : 0.f;
    float wB = (dd < CROWS) ? wbg[base + dd] : 0.f;
    float hv[CROWS];
#pragma unroll
    for (int r = 0; r < CROWS; ++r) {
      int j = __shfl(pj, r);
      hv[r] = h[(size_t)j * D + dd];
    }
    // scalar weight scans over lanes 0..15
    float incS = wS, incB = wB;
#pragma unroll
    for (int off = 1; off < CROWS; off <<= 1) {
      float uS = __shfl_up(incS, off);
      float uB = __shfl_up(incB, off);
      if (dd >= off) { incS += uS; incB += uB; }
    }
    float totS = __shfl(incS, CROWS - 1);
    float totB = __shfl(incB, CROWS - 1);
    if (dd < CROWS) {
      pl[base + dd] = incS - wS;           // exclusive prefix (small w)
      sl[base + dd] = totB - (incB - wB);  // inclusive suffix (big w)
    }
    if (dd == 0) {
      tots_sc[c] = totS;
      totb_sc[c] = totB;
      atomicAdd(&sups_c[c >> 4], totS);
      atomicAdd(&supb_c[c >> 4], totB);
    }
    // vector local scans (registers only)
    float runP = 0.f;
#pragma unroll
    for (int r = 0; r < CROWS; ++r) {
      Pl[(size_t)(base + r) * D + dd] = runP;
      runP += __shfl(wS, r) * hv[r];
    }
    tot_s[c * D + dd] = runP;
    float runS = 0.f;
#pragma unroll
    for (int r = CROWS - 1; r >= 0; --r) {
      runS += __shfl(wB, r) * hv[r];
      Sl[(size_t)(base + r) * D + dd] = runS;
    }
    tot_b[c * D + dd] = runS;
    atomicAdd(&sup_s[(c >> 4) * D + dd], runP);
    atomicAdd(&sup_b[(c >> 4) * D + dd], runS);
  } else {
    // binary-search blocks: ksplit[q] = #{keys < thrkey[q]} = lower_bound
#pragma unroll
    for (int i = 0; i < 32; ++i) sk[t + i * 256] = skey[t + i * 256];
    __syncthreads();
    int q = (bid - 128) * 256 + t;
    u64 thr = thrkey[q];
    int pos = 0;
#pragma unroll
    for (int b = 4096; b > 0; b >>= 1) {
      if (sk[pos + b - 1] < thr) pos += b;
    }
    ksplit[q] = pos;
  }
}

// K4: combine + output (absorbs old K3b). Per block (16 rows): build
// 33-entry super prefix/suffix tables in LDS from the atomic super totals,
// then per row: offset = super table[sc] + walk of <=15 chunk totals;
// add local scans at split k; ELU. k==N handled by branch (grand/0).
__global__ __launch_bounds__(256) void k4_out(
    const float* __restrict__ f1, const int* __restrict__ ksplit,
    const float* __restrict__ tot_s, const float* __restrict__ tot_b,
    const float* __restrict__ tots_sc, const float* __restrict__ totb_sc,
    const float* __restrict__ sup_s, const float* __restrict__ sup_b,
    const float* __restrict__ sups_c, const float* __restrict__ supb_c,
    const float* __restrict__ Pl, const float* __restrict__ Sl,
    const float* __restrict__ pl, const float* __restrict__ sl,
    float* __restrict__ out) {
  __shared__ float prefS[NSUP + 1][D];  // exclusive prefix of sup_s
  __shared__ float sufB[NSUP + 1][D];   // exclusive suffix of sup_b
  __shared__ float prefC[NSUP + 1], sufC[NSUP + 1];
  int t = threadIdx.x;
  int dd = t & 63, wv = t >> 6;
  // stage raw super totals: prefS[sc+1]=sup_s[sc], sufB[sc]=sup_b[sc]
#pragma unroll
  for (int i = 0; i < 8; ++i) {
    int idx = t + i * 256;
    int sc = idx >> 6, d2 = idx & 63;
    prefS[sc + 1][d2] = sup_s[idx];
    sufB[sc][d2] = sup_b[idx];
  }
  if (t < 64) prefS[0][t] = 0.f;
  else if (t < 128) sufB[NSUP][t - 64] = 0.f;
  else if (t < 160) prefC[t - 128 + 1] = sups_c[t - 128];
  else if (t < 192) sufC[t - 160] = supb_c[t - 160];
  else if (t == 192) prefC[0] = 0.f;
  __syncthreads();
  if (t < 64) {  // in-place prefix over supers, per dim
    for (int sc = 1; sc <= NSUP; ++sc) prefS[sc][t] += prefS[sc - 1][t];
  } else if (t < 128) {  // in-place exclusive suffix, per dim
    int d2 = t - 64;
    float run = 0.f;
    for (int sc = NSUP - 1; sc >= 0; --sc) {
      float raw = sufB[sc][d2];
      sufB[sc][d2] = run;
      run += raw;
    }
  } else if (t == 128) {
    for (int sc = 1; sc <= NSUP; ++sc) prefC[sc] += prefC[sc - 1];
  } else if (t == 129) {
    float run = 0.f;
    sufC[NSUP] = 0.f;
    for (int sc = NSUP - 1; sc >= 0; --sc) {
      float raw = sufC[sc];
      sufC[sc] = run;
      run += raw;
    }
  }
  __syncthreads();
  int r0 = blockIdx.x * 16;
#pragma unroll
  for (int ii = 0; ii < 4; ++ii) {
    int slot = wv * 4 + ii;
    int row = r0 + slot;
    int k = ksplit[row];  // wave-uniform -> broadcast load
    float f1v = f1[row];
    float e1 = expf(f1v), e2 = expf(0.2f * f1v);
    float Pv, Sv, ps, ss;
    if (k == N) {
      Pv = prefS[NSUP][dd];
      Sv = 0.f;
      ps = prefC[NSUP];
      ss = 0.f;
    } else {
      int c = k >> 4, sc = c >> 4, cb = sc << 4;
      float P = prefS[sc][dd], S = sufB[sc][dd];
      float pc = prefC[sc], bc = sufC[sc];
      int c2 = cb;  // prefix walk over chunks [cb, c)
      for (; c2 + 1 < c; c2 += 2) {
        P += tot_s[c2 * D + dd] + tot_s[(c2 + 1) * D + dd];
        pc += tots_sc[c2] + tots_sc[c2 + 1];
      }
      if (c2 < c) { P += tot_s[c2 * D + dd]; pc += tots_sc[c2]; }
      int ce = cb + 16;  // suffix walk over chunks (c, cb+16)
      c2 = c + 1;
      for (; c2 + 1 < ce; c2 += 2) {
        S += tot_b[c2 * D + dd] + tot_b[(c2 + 1) * D + dd];
        bc += totb_sc[c2] + totb_sc[c2 + 1];
      }
      if (c2 < ce) { S += tot_b[c2 * D + dd]; bc += totb_sc[c2]; }
      Pv = P + Pl[(size_t)k * D + dd];
      Sv = S + Sl[(size_t)k * D + dd];
      ps = pc + pl[k];
      ss = bc + sl[k];
    }
    float num = e1 * Sv + e2 * Pv;
    float den = e1 * ss + e2 * ps;
    float v = num / den;
    out[row * D + dd] = v > 0.f ? v : expm1f(v);
  }
}

extern "C" void kernel_launch(void* const* d_in, const int* in_sizes, int n_in,
                              void* d_out, int out_size, void* d_ws,
                              size_t ws_size, hipStream_t stream) {
  const float* x = (const float*)d_in[0];
  const float* Wt = (const float*)d_in[1];
  const float* a1 = (const float*)d_in[2];
  const float* b1 = (const float*)d_in[3];
  const float* a2 = (const float*)d_in[4];
  const float* b2 = (const float*)d_in[5];
  float* out = (float*)d_out;

  u64* key64 = (u64*)d_ws;
  u64* thrkey = key64 + N;
  u64* skey = thrkey + N;
  float* ws = (float*)(skey + N);
  float* h = ws;          ws += N * D;
  float* f1 = ws;         ws += N;
  float* f2v = ws;        ws += N;
  float* wsm = ws;        ws += N;
  float* wbg = ws;        ws += N;
  int* perm = (int*)ws;   ws += N;
  int* ksplit = (int*)ws; ws += N;
  float* Pl = ws;         ws += (size_t)N * D;
  float* Sl = ws;         ws += (size_t)N * D;
  float* tot_s = ws;      ws += CHUNKS * D;
  float* tot_b = ws;      ws += CHUNKS * D;
  float* pl = ws;         ws += N;
  float* sl = ws;         ws += N;
  float* tots_sc = ws;    ws += CHUNKS;
  float* totb_sc = ws;    ws += CHUNKS;
  float* sup_s = ws;      ws += NSUP * D;  // contiguous zeroed region start
  float* sup_b = ws;      ws += NSUP * D;
  float* sups_c = ws;     ws += NSUP;
  float* supb_c = ws;     ws += NSUP;

  k1_gemm<<<N / 16, 256, 0, stream>>>(x, Wt, a1, b1, a2, b2, h, f1, f2v,
                                      key64, thrkey, sup_s);
  k2_rank<<<N / 16, 256, 0, stream>>>(key64, f2v, perm, wsm, wbg, skey);
  k3_scan<<<160, 256, 0, stream>>>(h, perm, wsm, wbg, skey, thrkey, Pl, Sl,
                                   pl, sl, tot_s, tot_b, tots_sc, totb_sc,
                                   sup_s, sup_b, sups_c, supb_c, ksplit);
  k4_out<<<N / 16, 256, 0, stream>>>(f1, ksplit, tot_s, tot_b, tots_sc,
                                     totb_sc, sup_s, sup_b, sups_c, supb_c,
                                     Pl, Sl, pl, sl, out);
}

// Round 7
// 98.506 us; speedup vs baseline: 1.1141x; 1.1141x over previous
//
#include <hip/hip_runtime.h>
#include <math.h>

#define N 8192
#define D 64
#define CHUNKS 512
#define CROWS 16
#define KS 32       // key slices
#define SLICE 256   // N / KS
#define NQ (2 * N)  // 8192 element-rank queries + 8192 row-threshold queries

typedef unsigned long long u64;

__device__ __forceinline__ unsigned ordered_bits(float v) {
  unsigned u = __float_as_uint(v);
  return u ^ (((int)u >> 31) | 0x80000000u);
}

// K1: h = x@Wt (Wt column in regs, x row via shfl broadcast); f1/f2; 64-bit
// strictly-distinct sort keys + per-row threshold keys. 16 rows/block
// (512 blocks — more, smaller blocks drain faster; R7 showed 32/block regresses).
__global__ __launch_bounds__(256) void k1_gemm(
    const float* __restrict__ x, const float* __restrict__ Wt,
    const float* __restrict__ a1, const float* __restrict__ b1,
    const float* __restrict__ a2, const float* __restrict__ b2,
    float* __restrict__ h, float* __restrict__ f1, float* __restrict__ f2,
    u64* __restrict__ key64, u64* __restrict__ thrkey) {
  int t = threadIdx.x;
  int lane = t & 63, wv = t >> 6;
  float wcol[D];
#pragma unroll
  for (int k = 0; k < D; ++k) wcol[k] = Wt[k * D + lane];  // coalesced
  float a1d = a1[lane], a2d = a2[lane];
  float b1v = b1[0], b2v = b2[0];
  int rowBase = blockIdx.x * 16;
#pragma unroll
  for (int it = 0; it < 4; ++it) {
    int grow = rowBase + wv + it * 4;
    float xv = x[grow * D + lane];
    float acc = 0.f;
#pragma unroll
    for (int k = 0; k < D; ++k) acc += __shfl(xv, k) * wcol[k];
    h[grow * D + lane] = acc;
    float v1 = acc * a1d, v2 = acc * a2d;
#pragma unroll
    for (int off = 32; off > 0; off >>= 1) {
      v1 += __shfl_xor(v1, off);
      v2 += __shfl_xor(v2, off);
    }
    if (lane == 0) {
      float F1 = v1 + b1v, F2 = v2 + b2v;
      f1[grow] = F1;
      f2[grow] = F2;
      key64[grow] = ((u64)ordered_bits(F2) << 13) | (unsigned)grow;
      thrkey[grow] = ((u64)ordered_bits(-F1) << 13);
    }
  }
}

// K2a: partial counting rank. Block (g,s): query group g (1024 queries,
// 4/thread) vs key slice s (256 keys in LDS). part[s][q] = partial count.
// 512 blocks / 4 q-per-thread is the measured optimum (R6 vs R7).
__global__ __launch_bounds__(256) void k2a_count(
    const u64* __restrict__ key64, const u64* __restrict__ thrkey,
    int* __restrict__ part) {
  __shared__ u64 ksl[SLICE];
  int t = threadIdx.x;
  int g = blockIdx.x >> 5;        // 0..15
  int s = blockIdx.x & (KS - 1);  // 0..31
  ksl[t] = key64[s * SLICE + t];
  int q0 = g * 1024 + t;
  u64 qa = (q0 < N) ? key64[q0] : thrkey[q0 - N];
  int q1 = q0 + 256;
  u64 qb = (q1 < N) ? key64[q1] : thrkey[q1 - N];
  int q2 = q0 + 512;
  u64 qc = (q2 < N) ? key64[q2] : thrkey[q2 - N];
  int q3 = q0 + 768;
  u64 qd = (q3 < N) ? key64[q3] : thrkey[q3 - N];
  __syncthreads();
  int c0 = 0, c1 = 0, c2 = 0, c3 = 0;
#pragma unroll 8
  for (int l = 0; l < SLICE; ++l) {
    u64 k = ksl[l];
    c0 += (k < qa) ? 1 : 0;
    c1 += (k < qb) ? 1 : 0;
    c2 += (k < qc) ? 1 : 0;
    c3 += (k < qd) ? 1 : 0;
  }
  int* pb = part + s * NQ;
  pb[q0] = c0;
  pb[q1] = c1;
  pb[q2] = c2;
  pb[q3] = c3;
}

// K2b: reduce KS partials per query; scatter perm/weights or write ksplit.
__global__ __launch_bounds__(256) void k2b_reduce(
    const int* __restrict__ part, const float* __restrict__ f2,
    int* __restrict__ perm, float* __restrict__ wsm, float* __restrict__ wbg,
    int* __restrict__ ksplit) {
  int q = blockIdx.x * 256 + threadIdx.x;
  int tot = 0;
#pragma unroll
  for (int s = 0; s < KS; ++s) tot += part[s * NQ + q];
  if (q < N) {
    float v = f2[q];
    perm[tot] = q;
    wsm[tot] = expf(0.2f * v);
    wbg[tot] = expf(v);
  } else {
    ksplit[q - N] = tot;
  }
}

// K3: per-chunk LOCAL scans (1 chunk per wave, registers only) + totals.
__global__ __launch_bounds__(256) void k3_scan(
    const float* __restrict__ h, const int* __restrict__ perm,
    const float* __restrict__ wsm, const float* __restrict__ wbg,
    float* __restrict__ Pl, float* __restrict__ Sl,
    float* __restrict__ pl, float* __restrict__ sl,
    float* __restrict__ tot_s, float* __restrict__ tot_b,
    float* __restrict__ tots_sc, float* __restrict__ totb_sc) {
  int t = threadIdx.x, lane = t & 63, wv = t >> 6;
  int c = blockIdx.x * 4 + wv;
  int base = c * CROWS;
  int dd = lane;
  int pj = (dd < CROWS) ? perm[base + dd] : 0;
  float wS = (dd < CROWS) ? wsm[base + dd] : 0.f;
  float wB = (dd < CROWS) ? wbg[base + dd] : 0.f;
  float hv[CROWS];
#pragma unroll
  for (int r = 0; r < CROWS; ++r) {
    int j = __shfl(pj, r);
    hv[r] = h[(size_t)j * D + dd];
  }
  // scalar weight scans over lanes 0..15
  float incS = wS, incB = wB;
#pragma unroll
  for (int off = 1; off < CROWS; off <<= 1) {
    float uS = __shfl_up(incS, off);
    float uB = __shfl_up(incB, off);
    if (dd >= off) { incS += uS; incB += uB; }
  }
  float totS = __shfl(incS, CROWS - 1);
  float totB = __shfl(incB, CROWS - 1);
  if (dd < CROWS) {
    pl[base + dd] = incS - wS;           // exclusive prefix (small w)
    sl[base + dd] = totB - (incB - wB);  // inclusive suffix (big w)
  }
  if (dd == 0) { tots_sc[c] = totS; totb_sc[c] = totB; }
  // vector local scans (registers only)
  float runP = 0.f;
#pragma unroll
  for (int r = 0; r < CROWS; ++r) {
    Pl[(size_t)(base + r) * D + dd] = runP;
    runP += __shfl(wS, r) * hv[r];
  }
  tot_s[c * D + dd] = runP;
  float runS = 0.f;
#pragma unroll
  for (int r = CROWS - 1; r >= 0; --r) {
    runS += __shfl(wB, r) * hv[r];
    Sl[(size_t)(base + r) * D + dd] = runS;
  }
  tot_b[c * D + dd] = runS;
}

// K3b: chunk-offset scans, fully parallel. Blocks 0..63: vector prefix for
// dim=blk; 64..127: vector exclusive suffix for dim=blk-64; 128: scalars.
// 512-wide Hillis-Steele in LDS (9 steps).
__global__ __launch_bounds__(512) void k3b_offsets(
    const float* __restrict__ tot_s, const float* __restrict__ tot_b,
    const float* __restrict__ tots_sc, const float* __restrict__ totb_sc,
    float* __restrict__ off_s, float* __restrict__ off_b,
    float* __restrict__ poff, float* __restrict__ soff,
    float* __restrict__ Pl, float* __restrict__ Sl,
    float* __restrict__ pl, float* __restrict__ sl) {
  __shared__ float sc[512];
  int t = threadIdx.x;
  int blk = blockIdx.x;
  if (blk < 64) {
    int dd = blk;
    float v = tot_s[t * D + dd];
    sc[t] = v;
    __syncthreads();
    float inc = v;
#pragma unroll
    for (int off = 1; off < 512; off <<= 1) {
      float u_ = (t >= off) ? sc[t - off] : 0.f;
      __syncthreads();
      inc += u_;
      sc[t] = inc;
      __syncthreads();
    }
    off_s[t * D + dd] = inc - v;
    if (t == 511) off_s[CHUNKS * D + dd] = inc;  // sentinel
    if (t == 0) Pl[(size_t)N * D + dd] = 0.f;
  } else if (blk < 128) {
    int dd = blk - 64;
    int rc = 511 - t;
    float v = tot_b[rc * D + dd];
    sc[t] = v;
    __syncthreads();
    float inc = v;
#pragma unroll
    for (int off = 1; off < 512; off <<= 1) {
      float u_ = (t >= off) ? sc[t - off] : 0.f;
      __syncthreads();
      inc += u_;
      sc[t] = inc;
      __syncthreads();
    }
    off_b[rc * D + dd] = inc - v;  // exclusive suffix
    if (t == 0) {
      off_b[CHUNKS * D + dd] = 0.f;  // sentinel
      Sl[(size_t)N * D + dd] = 0.f;
    }
  } else {
    {  // scalar prefix over tots_sc
      float v = tots_sc[t];
      sc[t] = v;
      __syncthreads();
      float inc = v;
#pragma unroll
      for (int off = 1; off < 512; off <<= 1) {
        float u_ = (t >= off) ? sc[t - off] : 0.f;
        __syncthreads();
        inc += u_;
        sc[t] = inc;
        __syncthreads();
      }
      poff[t] = inc - v;
      if (t == 511) poff[CHUNKS] = inc;
      if (t == 0) pl[N] = 0.f;
    }
    __syncthreads();
    {  // scalar exclusive suffix over totb_sc
      int rc = 511 - t;
      float v = totb_sc[rc];
      sc[t] = v;
      __syncthreads();
      float inc = v;
#pragma unroll
      for (int off = 1; off < 512; off <<= 1) {
        float u_ = (t >= off) ? sc[t - off] : 0.f;
        __syncthreads();
        inc += u_;
        sc[t] = inc;
        __syncthreads();
      }
      soff[rc] = inc - v;
      if (t == 0) {
        soff[CHUNKS] = 0.f;
        sl[N] = 0.f;
      }
    }
  }
}

// K4: per (row, dim): combine global offset + local scan at split k; ELU.
__global__ __launch_bounds__(256) void k4_out(
    const float* __restrict__ f1, const int* __restrict__ ksplit,
    const float* __restrict__ off_s, const float* __restrict__ off_b,
    const float* __restrict__ poff, const float* __restrict__ soff,
    const float* __restrict__ Pl, const float* __restrict__ Sl,
    const float* __restrict__ pl, const float* __restrict__ sl,
    float* __restrict__ out) {
  int g = blockIdx.x * 256 + threadIdx.x;
  int row = g >> 6, dd = g & 63;
  float f1v = f1[row];
  int k = ksplit[row];
  int c = k >> 4;  // CROWS == 16; k == N -> sentinel chunk
  float e1 = expf(f1v), e2 = expf(0.2f * f1v);
  float Sv = off_b[c * D + dd] + Sl[(size_t)k * D + dd];
  float Pv = off_s[c * D + dd] + Pl[(size_t)k * D + dd];
  float num = e1 * Sv + e2 * Pv;
  float den = e1 * (soff[c] + sl[k]) + e2 * (poff[c] + pl[k]);
  float v = num / den;
  out[g] = v > 0.f ? v : expm1f(v);
}

extern "C" void kernel_launch(void* const* d_in, const int* in_sizes, int n_in,
                              void* d_out, int out_size, void* d_ws,
                              size_t ws_size, hipStream_t stream) {
  const float* x = (const float*)d_in[0];
  const float* Wt = (const float*)d_in[1];
  const float* a1 = (const float*)d_in[2];
  const float* b1 = (const float*)d_in[3];
  const float* a2 = (const float*)d_in[4];
  const float* b2 = (const float*)d_in[5];
  float* out = (float*)d_out;

  u64* key64 = (u64*)d_ws;
  u64* thrkey = key64 + N;
  float* ws = (float*)(thrkey + N);
  float* h = ws;          ws += N * D;
  float* f1 = ws;         ws += N;
  float* f2v = ws;        ws += N;
  float* wsm = ws;        ws += N;
  float* wbg = ws;        ws += N;
  int* perm = (int*)ws;   ws += N;
  int* ksplit = (int*)ws; ws += N;
  int* part = (int*)ws;   ws += KS * NQ;
  float* Pl = ws;         ws += (size_t)(N + 1) * D;
  float* Sl = ws;         ws += (size_t)(N + 1) * D;
  float* tot_s = ws;      ws += CHUNKS * D;
  float* tot_b = ws;      ws += CHUNKS * D;
  float* off_s = ws;      ws += (CHUNKS + 1) * D;
  float* off_b = ws;      ws += (CHUNKS + 1) * D;
  float* pl = ws;         ws += (N + 1);
  float* sl = ws;         ws += (N + 1);
  float* tots_sc = ws;    ws += CHUNKS;
  float* totb_sc = ws;    ws += CHUNKS;
  float* poff = ws;       ws += (CHUNKS + 1);
  float* soff = ws;       ws += (CHUNKS + 1);

  k1_gemm<<<N / 16, 256, 0, stream>>>(x, Wt, a1, b1, a2, b2, h, f1, f2v,
                                      key64, thrkey);
  k2a_count<<<16 * KS, 256, 0, stream>>>(key64, thrkey, part);
  k2b_reduce<<<NQ / 256, 256, 0, stream>>>(part, f2v, perm, wsm, wbg, ksplit);
  k3_scan<<<CHUNKS / 4, 256, 0, stream>>>(h, perm, wsm, wbg, Pl, Sl, pl, sl,
                                          tot_s, tot_b, tots_sc, totb_sc);
  k3b_offsets<<<129, 512, 0, stream>>>(tot_s, tot_b, tots_sc, totb_sc, off_s,
                                       off_b, poff, soff, Pl, Sl, pl, sl);
  k4_out<<<(N * D) / 256, 256, 0, stream>>>(f1, ksplit, off_s, off_b, poff,
                                            soff, Pl, Sl, pl, sl, out);
}